// Round 10
// baseline (138.544 us; speedup 1.0000x reference)
//
#include <hip/hip_runtime.h>
#include <hip/hip_bf16.h>

// B=4, S=4096, D=2048, H=16, dh=128, R=4, WIN=128, Cs=1024, ws=3968.
// Chunks 992..1023 are the only ones with live attention; chunks <=991 collapse
// to v[:,0,:]. Resize rows 0..3965 per batch broadcast the base chunk row.
//
// Structure (5 dispatches):
//   prep_means  : Q chunk-means -> bf16 Aq (0.5 MB; only prematerialized input)
//   qkv_kernel  : 128x128/BK32 GEMM, A = f32 window read DIRECT (fused cvt) or
//                 Aq bf16; W = f32 read direct (fused cvt). split-K=2 -> bf16
//                 partial slices. 4 blocks/CU, stride-40 LDS pad.
//   attn_kernel : sums 2 partial slices during staging, 32x128 masked softmax
//   o_kernel    : same body, split-K=2 -> 2 f32 Yo partial slices
//   resize_kernel: sums 2 Yo slices, clamped lerp upsample -> d_out

typedef __attribute__((ext_vector_type(8))) short short8;
typedef __attribute__((ext_vector_type(4))) float f32x4;

#define LDP 40                    // LDS row stride in shorts (80 B: 16B-aligned, 2-way banks)
#define QP_SLICE  (128 * 2048)    // shorts per Q partial slice
#define KV_SLICE  (512 * 2048)    // shorts per K/V partial slice
#define YO_STRIDE (132 * 2048)    // floats per Yo partial slice

__device__ __forceinline__ unsigned short f2bf(float f){
  unsigned int x = __float_as_uint(f);
  return (unsigned short)((x + 0x7fffu + ((x >> 16) & 1u)) >> 16);
}
__device__ __forceinline__ float bf2f(unsigned short u){
  return __uint_as_float(((unsigned int)u) << 16);
}
__device__ __forceinline__ float bflo(unsigned int u){ return __uint_as_float(u << 16); }
__device__ __forceinline__ float bfhi(unsigned int u){ return __uint_as_float(u & 0xffff0000u); }
__device__ __forceinline__ unsigned int pk2(float lo, float hi){
  return ((unsigned int)f2bf(hi) << 16) | (unsigned int)f2bf(lo);
}
__device__ __forceinline__ short8 cvt8(float4 x, float4 y){
  union { unsigned int u[4]; short8 s; } r;
  r.u[0] = pk2(x.x, x.y); r.u[1] = pk2(x.z, x.w);
  r.u[2] = pk2(y.x, y.y); r.u[3] = pk2(y.z, y.w);
  return r.s;
}

// ---------- prep: Q chunk-means -> bf16 ----------
__global__ __launch_bounds__(256) void prep_means(
    const float* __restrict__ inp, unsigned short* __restrict__ Aq)
{
  const int idx = blockIdx.x * 256 + threadIdx.x;   // [0, 32768)
  const int b = idx >> 13;
  const int c = (idx >> 8) & 31;
  const int d8 = (idx & 255) * 8;
  const float* p = inp + ((size_t)b * 4096 + 3968 + 4 * c) * 2048 + d8;
  float4 x0 = *(const float4*)(p);
  float4 x1 = *(const float4*)(p + 2048);
  float4 x2 = *(const float4*)(p + 4096);
  float4 x3 = *(const float4*)(p + 6144);
  float4 y0 = *(const float4*)(p + 4);
  float4 y1 = *(const float4*)(p + 2052);
  float4 y2 = *(const float4*)(p + 4100);
  float4 y3 = *(const float4*)(p + 6148);
  float4 xm, ym;
  xm.x = 0.25f * (x0.x + x1.x + x2.x + x3.x);
  xm.y = 0.25f * (x0.y + x1.y + x2.y + x3.y);
  xm.z = 0.25f * (x0.z + x1.z + x2.z + x3.z);
  xm.w = 0.25f * (x0.w + x1.w + x2.w + x3.w);
  ym.x = 0.25f * (y0.x + y1.x + y2.x + y3.x);
  ym.y = 0.25f * (y0.y + y1.y + y2.y + y3.y);
  ym.z = 0.25f * (y0.z + y1.z + y2.z + y3.z);
  ym.w = 0.25f * (y0.w + y1.w + y2.w + y3.w);
  *(short8*)&Aq[((size_t)b * 32 + c) * 2048 + d8] = cvt8(xm, ym);
}

// ---- GEMM slice: C[row0..+127, n0..+127] = A[., kbase..+32*nsteps) @ W^T.
// BK=32, 4 waves (2x2 of 64x64), 16x16x32 bf16 MFMA, register prefetch +
// single padded LDS buffer (2 barriers/step). AMODE: 0 = bf16 rows, 1 = f32
// window rows from inp. W is always f32, converted in registers.
template<int AMODE, bool OUT_BF16>
__device__ __forceinline__ void gemm_body(
    const void* __restrict__ Abase, const float* __restrict__ W,
    unsigned short* __restrict__ Cb, float* __restrict__ Cf,
    int M, int row0, int n0, int kbase, int nsteps,
    unsigned short* As, unsigned short* Bs)
{
  const int tid  = threadIdx.x;
  const int lane = tid & 63;
  const int wid  = tid >> 6;
  const int wr = wid >> 1, wc = wid & 1;

  const int arow = tid >> 1;          // 0..127 staging row
  const int h    = (tid & 1) * 16;    // 16-elem half of the 32-col strip

  int ga = row0 + arow; if (ga > M - 1) ga = M - 1;
  const float*          ArowF = nullptr;
  const unsigned short* ArowB = nullptr;
  if constexpr (AMODE == 1)
    ArowF = (const float*)Abase + ((size_t)(ga >> 7) * 4096 + 3968 + (ga & 127)) * 2048;
  else
    ArowB = (const unsigned short*)Abase + (size_t)ga * 2048;
  const float* Wrow = W + (size_t)(n0 + arow) * 2048;

  f32x4 acc[4][4] = {};
  short8 a0, a1, b0, b1;

  // load + stage K-strip 0
  {
    const int kt = kbase;
    if constexpr (AMODE == 1){
      a0 = cvt8(*(const float4*)(ArowF + kt + h), *(const float4*)(ArowF + kt + h + 4));
      a1 = cvt8(*(const float4*)(ArowF + kt + h + 8), *(const float4*)(ArowF + kt + h + 12));
    } else {
      a0 = *(const short8*)(ArowB + kt + h);
      a1 = *(const short8*)(ArowB + kt + h + 8);
    }
    b0 = cvt8(*(const float4*)(Wrow + kt + h), *(const float4*)(Wrow + kt + h + 4));
    b1 = cvt8(*(const float4*)(Wrow + kt + h + 8), *(const float4*)(Wrow + kt + h + 12));
    *(short8*)&As[arow * LDP + h]     = a0;
    *(short8*)&As[arow * LDP + h + 8] = a1;
    *(short8*)&Bs[arow * LDP + h]     = b0;
    *(short8*)&Bs[arow * LDP + h + 8] = b1;
  }
  __syncthreads();

  for (int t = 0; t < nsteps; ++t){
    const bool pf = (t + 1) < nsteps;
    if (pf){
      const int kt = kbase + (t + 1) * 32;
      if constexpr (AMODE == 1){
        a0 = cvt8(*(const float4*)(ArowF + kt + h), *(const float4*)(ArowF + kt + h + 4));
        a1 = cvt8(*(const float4*)(ArowF + kt + h + 8), *(const float4*)(ArowF + kt + h + 12));
      } else {
        a0 = *(const short8*)(ArowB + kt + h);
        a1 = *(const short8*)(ArowB + kt + h + 8);
      }
      b0 = cvt8(*(const float4*)(Wrow + kt + h), *(const float4*)(Wrow + kt + h + 4));
      b1 = cvt8(*(const float4*)(Wrow + kt + h + 8), *(const float4*)(Wrow + kt + h + 12));
    }
    // compute on current LDS tile
    {
      short8 av[4], bv[4];
      const int ko = (lane >> 4) * 8;
      #pragma unroll
      for (int f = 0; f < 4; ++f)
        av[f] = *(const short8*)&As[(wr * 64 + f * 16 + (lane & 15)) * LDP + ko];
      #pragma unroll
      for (int n = 0; n < 4; ++n)
        bv[n] = *(const short8*)&Bs[(wc * 64 + n * 16 + (lane & 15)) * LDP + ko];
      #pragma unroll
      for (int f = 0; f < 4; ++f)
        #pragma unroll
        for (int n = 0; n < 4; ++n)
          acc[f][n] = __builtin_amdgcn_mfma_f32_16x16x32_bf16(av[f], bv[n], acc[f][n], 0, 0, 0);
    }
    __syncthreads();
    if (pf){
      *(short8*)&As[arow * LDP + h]     = a0;
      *(short8*)&As[arow * LDP + h + 8] = a1;
      *(short8*)&Bs[arow * LDP + h]     = b0;
      *(short8*)&Bs[arow * LDP + h + 8] = b1;
      __syncthreads();
    }
  }

  // epilogue: C/D layout col=lane&15, row=(lane>>4)*4+reg
  #pragma unroll
  for (int f = 0; f < 4; ++f){
    #pragma unroll
    for (int n = 0; n < 4; ++n){
      const int col = n0 + wc * 64 + n * 16 + (lane & 15);
      #pragma unroll
      for (int r = 0; r < 4; ++r){
        const int row = row0 + wr * 64 + f * 16 + (lane >> 4) * 4 + r;
        if (row < M){
          if (OUT_BF16) Cb[(size_t)row * 2048 + col] = f2bf(acc[f][n][r]);
          else          Cf[(size_t)row * 2048 + col] = acc[f][n][r];
        }
      }
    }
  }
}

// grid (16 nt, 9 gy, 2 ksp): gy 0 -> Q, 1..4 -> K (mt=gy-1), 5..8 -> V (mt=gy-5)
__global__ __launch_bounds__(256, 4) void qkv_kernel(
    const float* __restrict__ inp, const unsigned short* __restrict__ Aq,
    const float* __restrict__ Wq, const float* __restrict__ Wk, const float* __restrict__ Wv,
    unsigned short* __restrict__ Qp, unsigned short* __restrict__ Kp,
    unsigned short* __restrict__ Vp)
{
  __shared__ __align__(16) unsigned short As[128 * LDP];
  __shared__ __align__(16) unsigned short Bs[128 * LDP];
  const int nt = blockIdx.x, gy = blockIdx.y, ksp = blockIdx.z;
  if (gy == 0){
    gemm_body<0, true>(Aq, Wq, Qp + ksp * QP_SLICE, nullptr,
                       128, 0, nt * 128, ksp * 1024, 32, As, Bs);
  } else if (gy < 5){
    gemm_body<1, true>(inp, Wk, Kp + ksp * KV_SLICE, nullptr,
                       512, (gy - 1) * 128, nt * 128, ksp * 1024, 32, As, Bs);
  } else {
    gemm_body<1, true>(inp, Wv, Vp + ksp * KV_SLICE, nullptr,
                       512, (gy - 5) * 128, nt * 128, ksp * 1024, 32, As, Bs);
  }
}

// O-projection: grid (16 nt, 2 mt, 2 ksp) -> 2 f32 Yo partial slices
__global__ __launch_bounds__(256, 4) void o_kernel(
    const unsigned short* __restrict__ Ao, const float* __restrict__ Wo,
    float* __restrict__ Yop)
{
  __shared__ __align__(16) unsigned short As[128 * LDP];
  __shared__ __align__(16) unsigned short Bs[128 * LDP];
  gemm_body<0, false>(Ao, Wo, nullptr, Yop + (size_t)blockIdx.z * YO_STRIDE,
                      132, blockIdx.y * 128, blockIdx.x * 128, blockIdx.z * 1024, 32,
                      As, Bs);
}

// ---------------- attention: chunks 992..1023 only, per (b,h) block ----------------
// Sums the 2 bf16 split-K partial slices of Q/K/V during LDS staging.
__global__ __launch_bounds__(256) void attn_kernel(
    const unsigned short* __restrict__ Qp, const unsigned short* __restrict__ Kp,
    const unsigned short* __restrict__ Vp, const int* __restrict__ amask,
    unsigned short* __restrict__ Ao)
{
  const int b = blockIdx.x >> 4;
  const int h = blockIdx.x & 15;
  __shared__ float Qs[32][129];
  __shared__ unsigned int Ks[128][65];
  __shared__ unsigned int Vs[128][65];
  __shared__ float Wt[32][132];
  __shared__ float msk[128];
  const int tid = threadIdx.x;

  for (int i = tid; i < 32 * 128; i += 256){
    int cq = i >> 7, d = i & 127;
    size_t off = (size_t)(b * 32 + cq) * 2048 + h * 128 + d;
    Qs[cq][d] = bf2f(Qp[off]) + bf2f(Qp[off + QP_SLICE]);
  }
  for (int i = tid; i < 128 * 64; i += 256){
    int j = i >> 6, du = i & 63;
    size_t off = (size_t)(b * 128 + j) * 2048 + h * 128 + du * 2;
    unsigned int k0 = *(const unsigned int*)(Kp + off);
    unsigned int k1 = *(const unsigned int*)(Kp + off + KV_SLICE);
    unsigned int v0 = *(const unsigned int*)(Vp + off);
    unsigned int v1 = *(const unsigned int*)(Vp + off + KV_SLICE);
    Ks[j][du] = pk2(bflo(k0) + bflo(k1), bfhi(k0) + bfhi(k1));
    Vs[j][du] = pk2(bflo(v0) + bflo(v1), bfhi(v0) + bfhi(v1));
  }
  if (tid < 128){
    msk[tid] = (amask[b * 4096 + 3968 + tid] != 0) ? 1.f : 0.f;
    size_t off = (size_t)(b * 128) * 2048 + h * 128 + tid;
    Ao[(size_t)(b * 33) * 2048 + h * 128 + tid] =
        f2bf(bf2f(Vp[off]) + bf2f(Vp[off + KV_SLICE]));
  }
  __syncthreads();

  const int cq = tid >> 3, jg = tid & 7;
  const int jmax = 4 * cq + 3;   // causal: j <= 4*cq+3 for chunk 992+cq
  const float scale = 0.088388347648318447f; // 1/sqrt(128)

  float s[16];
  {
    float sacc[16];
    #pragma unroll
    for (int jj = 0; jj < 16; ++jj) sacc[jj] = 0.f;
    for (int du = 0; du < 64; ++du){
      float q0 = Qs[cq][2 * du], q1 = Qs[cq][2 * du + 1];
      #pragma unroll
      for (int jj = 0; jj < 16; ++jj){
        unsigned int u = Ks[jg * 16 + jj][du];
        sacc[jj] += q0 * bflo(u) + q1 * bfhi(u);
      }
    }
    #pragma unroll
    for (int jj = 0; jj < 16; ++jj){
      int j = jg * 16 + jj;
      bool ok = (j <= jmax) && (msk[j] > 0.5f);
      s[jj] = ok ? sacc[jj] * scale : -1e9f;
    }
  }
  float m = s[0];
  #pragma unroll
  for (int jj = 1; jj < 16; ++jj) m = fmaxf(m, s[jj]);
  #pragma unroll
  for (int off = 1; off < 8; off <<= 1) m = fmaxf(m, __shfl_xor(m, off, 8));
  float sum = 0.f;
  #pragma unroll
  for (int jj = 0; jj < 16; ++jj){ s[jj] = expf(s[jj] - m); sum += s[jj]; }
  #pragma unroll
  for (int off = 1; off < 8; off <<= 1) sum += __shfl_xor(sum, off, 8);
  const float inv = 1.f / sum;
  #pragma unroll
  for (int jj = 0; jj < 16; ++jj) Wt[cq][jg * 16 + jj] = s[jj] * inv;
  __syncthreads();

  const int dg = tid & 7;
  float o[16];
  #pragma unroll
  for (int e = 0; e < 16; ++e) o[e] = 0.f;
  for (int j = 0; j < 128; ++j){
    float w = Wt[cq][j];
    #pragma unroll
    for (int du = 0; du < 8; ++du){
      unsigned int u = Vs[j][dg * 8 + du];
      o[2 * du]     += w * bflo(u);
      o[2 * du + 1] += w * bfhi(u);
    }
  }
  unsigned short* dst = Ao + (size_t)(b * 33 + 1 + cq) * 2048 + h * 128 + dg * 16;
  #pragma unroll
  for (int e = 0; e < 16; ++e) dst[e] = f2bf(o[e]);
}

// -------- resize: sum 2 Yo slices, linear upsample Cs=1024 -> S=4096 --------
__global__ __launch_bounds__(256) void resize_kernel(
    const float* __restrict__ Yop, float* __restrict__ out)
{
  const int rowid = blockIdx.x;       // b*4096 + i
  const int b = rowid >> 12;
  const int i = rowid & 4095;
  float c  = i * 0.25f - 0.375f;
  float fl = floorf(c);
  int   j0 = (int)fl;
  float f  = c - fl;
  int   j1 = j0 + 1;
  j0 = max(0, min(j0, 1023));
  j1 = max(0, min(j1, 1023));
  const int ri0 = b * 33 + (j0 <= 991 ? 0 : j0 - 991);
  const int ri1 = b * 33 + (j1 <= 991 ? 0 : j1 - 991);
  const float* r0 = Yop + (size_t)ri0 * 2048;
  const float* r1 = Yop + (size_t)ri1 * 2048;
  float* op = out + (size_t)rowid * 2048;
  const int t = threadIdx.x;
  const bool same = (ri0 == ri1);
  #pragma unroll
  for (int q = 0; q < 2; ++q){
    int d = q * 1024 + t * 4;
    float4 a0 = *(const float4*)(r0 + d);
    float4 a1 = *(const float4*)(r0 + d + YO_STRIDE);
    float4 a;
    a.x = a0.x + a1.x; a.y = a0.y + a1.y; a.z = a0.z + a1.z; a.w = a0.w + a1.w;
    float4 o = a;
    if (!same){
      float4 b0 = *(const float4*)(r1 + d);
      float4 b1 = *(const float4*)(r1 + d + YO_STRIDE);
      float4 bb;
      bb.x = b0.x + b1.x; bb.y = b0.y + b1.y; bb.z = b0.z + b1.z; bb.w = b0.w + b1.w;
      o.x = a.x + f * (bb.x - a.x);
      o.y = a.y + f * (bb.y - a.y);
      o.z = a.z + f * (bb.z - a.z);
      o.w = a.w + f * (bb.w - a.w);
    }
    *(float4*)(op + d) = o;
  }
}

extern "C" void kernel_launch(void* const* d_in, const int* in_sizes, int n_in,
                              void* d_out, int out_size, void* d_ws, size_t ws_size,
                              hipStream_t stream)
{
  const float* inp   = (const float*)d_in[0];
  const int*   amask = (const int*)d_in[1];
  const float* Wq = (const float*)d_in[2];
  const float* Wk = (const float*)d_in[3];
  const float* Wv = (const float*)d_in[4];
  const float* Wo = (const float*)d_in[5];
  float* out = (float*)d_out;

  char* ws = (char*)d_ws;
  unsigned short* Aq  = (unsigned short*)(ws);             // 128 x 2048 bf16 (chunk means)
  unsigned short* Qp  = (unsigned short*)(ws + 524288);    // 2 x [128x2048] bf16 partials
  unsigned short* Kp  = (unsigned short*)(ws + 1572864);   // 2 x [512x2048] bf16 partials
  unsigned short* Vp  = (unsigned short*)(ws + 5767168);   // 2 x [512x2048] bf16 partials
  unsigned short* Ao  = (unsigned short*)(ws + 9961472);   // 132 x 2048 bf16
  float*          Yop = (float*)(ws + 10502144);           // 2 x [132x2048] f32 partials

  prep_means<<<128, 256, 0, stream>>>(inp, Aq);
  qkv_kernel<<<dim3(16, 9, 2), 256, 0, stream>>>(inp, Aq, Wq, Wk, Wv, Qp, Kp, Vp);
  attn_kernel<<<64, 256, 0, stream>>>(Qp, Kp, Vp, amask, Ao);
  o_kernel<<<dim3(16, 2, 2), 256, 0, stream>>>(Ao, Wo, Yop);
  resize_kernel<<<16384, 256, 0, stream>>>(Yop, out);
}